// Round 7
// baseline (139.441 us; speedup 1.0000x reference)
//
#include <hip/hip_runtime.h>

// Problem constants (B=1)
#define SS 256
#define DD 512
#define NN 8
#define HH 64

typedef __bf16 bf16x8 __attribute__((ext_vector_type(8)));
typedef __bf16 bf16x4 __attribute__((ext_vector_type(4)));
typedef float  floatx4 __attribute__((ext_vector_type(4)));

// ---------------------------------------------------------------------------
// Kernel A: projections via MFMA 16x16x32 bf16.
//   m=0: K1 = x@W_K1 + b_K1      -> f32 [n][256][64]
//   m=1: K2 = x@W_K2 + b_K2      -> bf16, xor-swizzled 16B chunks (attn LDS
//                                   layout: elem (p,h) at chunk (h>>3)^(p&7))
//   m=2: Qs = (x@W_Q + b_Q)/64   -> f32
//   m=3: VA = x@W_V12[:, :D]     -> bf16 plain [n][256][64]
//   m=4: VB = x@W_V12[:, D:]     -> bf16 plain
//   m=5: out[q,:] = b_O          (bias init for attn's atomic accumulation;
//                                 stream order guarantees visibility)
// grid = 6*64 = 384 blocks, 256 threads.
// ---------------------------------------------------------------------------
__global__ __launch_bounds__(256) void proj_kernel(
    const float* __restrict__ x,
    const float* __restrict__ WK1, const float* __restrict__ WK2,
    const float* __restrict__ WQ,  const float* __restrict__ WV12,
    const float* __restrict__ bK1, const float* __restrict__ bK2,
    const float* __restrict__ bQ,  const float* __restrict__ bO,
    float* __restrict__ K1b, float* __restrict__ Qb,
    __bf16* __restrict__ K2bf, __bf16* __restrict__ VAbf,
    __bf16* __restrict__ VBbf, float* __restrict__ outp)
{
    const int blk = blockIdx.x;
    const int m  = blk >> 6;        // which matrix (0..5)
    const int tid  = threadIdx.x;

    __shared__ __bf16 xsh[32 * DD];   // 32 KB, xor-swizzled 16B chunks

    if (m == 5) {                     // bias init of out (whole block branches)
        const int idx = blk & 63;
        const int q = idx * 4 + (tid >> 6);
        const int d = (tid & 63) * 8;
        const float4 b0 = *(const float4*)(bO + d);
        const float4 b1 = *(const float4*)(bO + d + 4);
        *(float4*)(outp + q * DD + d)     = b0;
        *(float4*)(outp + q * DD + d + 4) = b1;
        return;
    }

    const int pt = blk & 7;         // 8 p-tiles of 32 rows
    const int n  = (blk >> 3) & 7;  // head
    const int lane = tid & 63;
    const int wid  = tid >> 6;
    const int r15  = lane & 15;     // MFMA M/N index
    const int quad = lane >> 4;     // MFMA k-group / row-group
    const int p0 = pt * 32;

    const float* W;
    if (m == 0)      W = WK1  + n * DD * HH;
    else if (m == 1) W = WK2  + n * DD * HH;
    else if (m == 2) W = WQ   + n * DD * HH;
    else if (m == 3) W = WV12 + n * 2 * DD * HH;
    else             W = WV12 + n * 2 * DD * HH + DD * HH;

    // ---- stage x rows p0..p0+31 (f32 -> bf16, swizzled) ----------------------
    for (int it = 0; it < 8; ++it) {
        const int idx = tid + it * 256;   // chunk id 0..2047 (32 rows x 64)
        const int row = idx >> 6;
        const int c8  = idx & 63;
        const float4 xa = *(const float4*)(x + (p0 + row) * DD + c8 * 8);
        const float4 xb = *(const float4*)(x + (p0 + row) * DD + c8 * 8 + 4);
        bf16x8 v;
        v[0]=(__bf16)xa.x; v[1]=(__bf16)xa.y; v[2]=(__bf16)xa.z; v[3]=(__bf16)xa.w;
        v[4]=(__bf16)xb.x; v[5]=(__bf16)xb.y; v[6]=(__bf16)xb.z; v[7]=(__bf16)xb.w;
        *(bf16x8*)&xsh[row * DD + ((c8 ^ (row & 7)) << 3)] = v;
    }
    __syncthreads();

    // ---- MFMA: wave w -> h-tile w, both p-sub-tiles; K = 512 -----------------
    const int h0 = wid << 4;
    const int swz = r15 & 7;          // row swizzle key
    floatx4 C0 = {0.f,0.f,0.f,0.f}, C1 = {0.f,0.f,0.f,0.f};
    for (int kk = 0; kk < 16; ++kk) {
        const int c8 = (kk << 2) + quad;                 // 16B chunk of k-range
        const bf16x8 A0 = *(const bf16x8*)&xsh[ r15       * DD + ((c8 ^ swz) << 3)];
        const bf16x8 A1 = *(const bf16x8*)&xsh[(16 + r15) * DD + ((c8 ^ swz) << 3)];
        const float* Wp = W + (kk * 32 + quad * 8) * HH + h0 + r15;
        bf16x8 Bv;
        #pragma unroll
        for (int j = 0; j < 8; ++j) Bv[j] = (__bf16)Wp[j * HH];
        C0 = __builtin_amdgcn_mfma_f32_16x16x32_bf16(A0, Bv, C0, 0, 0, 0);
        C1 = __builtin_amdgcn_mfma_f32_16x16x32_bf16(A1, Bv, C1, 0, 0, 0);
    }

    // ---- epilogue: bias, scale, store (C: col=r15 -> h, row=quad*4+i -> p) ---
    float bv = 0.f;
    if (m == 0)      bv = bK1[n * HH + h0 + r15];
    else if (m == 1) bv = bK2[n * HH + h0 + r15];
    else if (m == 2) bv = bQ[n * HH + h0 + r15];

    if (m == 1) {
        const int h = h0 + r15;
        const int c8 = h >> 3;
        #pragma unroll
        for (int i = 0; i < 4; ++i) {
            int p = p0 + quad * 4 + i;
            K2bf[(n * SS + p) * HH + ((c8 ^ (p & 7)) << 3) + (h & 7)] =
                (__bf16)(C0[i] + bv);
            p += 16;
            K2bf[(n * SS + p) * HH + ((c8 ^ (p & 7)) << 3) + (h & 7)] =
                (__bf16)(C1[i] + bv);
        }
    } else if (m >= 3) {
        __bf16* outb = (m == 3) ? VAbf : VBbf;
        #pragma unroll
        for (int i = 0; i < 4; ++i) {
            const int p = p0 + quad * 4 + i;
            outb[(n * SS + p) * HH + h0 + r15]      = (__bf16)C0[i];
            outb[(n * SS + p + 16) * HH + h0 + r15] = (__bf16)C1[i];
        }
    } else {
        float* outb = (m == 0) ? K1b : Qb;
        const float scale = (m == 2) ? (1.0f / 64.0f) : 1.0f;  // fold 1/H into Q
        #pragma unroll
        for (int i = 0; i < 4; ++i) {
            const int p = p0 + quad * 4 + i;
            outb[(n * SS + p) * HH + h0 + r15]      = (C0[i] + bv) * scale;
            outb[(n * SS + p + 16) * HH + h0 + r15] = (C1[i] + bv) * scale;
        }
    }
}

// ---------------------------------------------------------------------------
// Kernel B: block = (n, q-pair {g, 255-g}), 1024 blocks = 4 blocks/CU.
// Changes vs R6 (latency-chain attack):
//  * column sums: all-64-lane fire-and-forget LDS atomicAdd (ds_add_f32) of
//    the per-lane 4-element partial -- removes 2 lgkmcnt-blocking shuffles
//    from the per-tile critical path.
//  * t-loop unrolled 2x (tiles t0, t0+16 in flight) -> 2-4 independent
//    MFMA->exp chains per wave.
// Masked entries are exactly 0 in the reference (exp underflow) so excluding
// them is exact; q<2 rows fully masked -> preset uniform 1/256.
// z[q,n,:] = (sum_s a_s VA[s] + sum_t c_t VB[t]) * invZ + b_V12, then the
// block's out-contribution z . WO[n*64:(n+1)*64, :] is atomicAdd-ed into out
// (bias pre-written by proj; stream order + device-scope atomics = safe).
// ---------------------------------------------------------------------------
__global__ __launch_bounds__(256, 4) void attn_kernel(
    const float* __restrict__ K1b, const __bf16* __restrict__ K2bf,
    const float* __restrict__ Qb,  const __bf16* __restrict__ VAbf,
    const __bf16* __restrict__ VBbf, const float* __restrict__ bV12,
    const float* __restrict__ WO, float* __restrict__ outp)
{
    const int n = blockIdx.x & 7;            // %8: same head -> same XCD L2
    const int g = (int)(blockIdx.x >> 3);    // 0..127
    int qs2[2];
    qs2[0] = g; qs2[1] = 255 - g;
    const int qmax = qs2[1];                 // >= 128 always

    const int tid  = threadIdx.x;
    const int lane = tid & 63;
    const int wid  = tid >> 6;
    const int r15  = lane & 15;   // MFMA free-dim (t) index
    const int quad = lane >> 4;   // MFMA k-group / s-row group

    __shared__ __bf16 K2sh[SS * HH];   // 32 KB, already swizzled by proj
    __shared__ float qsh[2][HH];       // q rows; later reused for final z rows
    __shared__ float a_lds[2][SS];
    __shared__ float c_lds[2][SS];
    __shared__ float zred[2][4][HH];
    __shared__ float red[2][4];

    // ---- stage K2 (plain bf16 copy) + the 2 q rows ---------------------------
    {
        const __bf16* src = K2bf + (n << 8) * HH;
        for (int it = 0; it < 8; ++it) {
            const int idx = tid + it * 256;  // 2048 16B chunks
            *(bf16x8*)&K2sh[idx * 8] = *(const bf16x8*)&src[idx * 8];
        }
        if (tid < 32) {
            const int qi = tid >> 4, c = tid & 15;
            const float4 qv = *(const float4*)(Qb + ((n << 8) + qs2[qi]) * HH + c * 4);
            *(float4*)&qsh[qi][c * 4] = qv;
        }
        #pragma unroll
        for (int qi = 0; qi < 2; ++qi) {
            const float init = (qs2[qi] < 2) ? (1.0f / SS) : 0.f;
            a_lds[qi][tid] = init;
            c_lds[qi][tid] = init;
        }
    }
    __syncthreads();

    // ---- score strips --------------------------------------------------------
    #pragma unroll
    for (int j = 0; j < 4; ++j) {
        int strip;
        if (j == 0) strip = wid;
        else if (j == 1) strip = 7 - wid;
        else if (j == 2) strip = 8 + wid;
        else strip = 15 - wid;
        const int s0 = strip << 4;
        if (s0 + 2 > qmax) continue;

        // k1 fragment rows (shared across the 2 q's)
        const float* k1p = K1b + ((n << 8) + s0 + r15) * HH;
        const float4 ka = *(const float4*)(k1p + quad * 8);
        const float4 kb = *(const float4*)(k1p + quad * 8 + 4);
        const float4 kc = *(const float4*)(k1p + 32 + quad * 8);
        const float4 kd = *(const float4*)(k1p + 32 + quad * 8 + 4);

        bf16x8 a0q[2], a1q[2];
        #pragma unroll
        for (int qi = 0; qi < 2; ++qi) {
            const float4 qa = *(const float4*)&qsh[qi][quad * 8];
            const float4 qb_ = *(const float4*)&qsh[qi][quad * 8 + 4];
            const float4 qc = *(const float4*)&qsh[qi][32 + quad * 8];
            const float4 qd = *(const float4*)&qsh[qi][32 + quad * 8 + 4];
            a0q[qi][0] = (__bf16)(ka.x * qa.x); a0q[qi][1] = (__bf16)(ka.y * qa.y);
            a0q[qi][2] = (__bf16)(ka.z * qa.z); a0q[qi][3] = (__bf16)(ka.w * qa.w);
            a0q[qi][4] = (__bf16)(kb.x * qb_.x); a0q[qi][5] = (__bf16)(kb.y * qb_.y);
            a0q[qi][6] = (__bf16)(kb.z * qb_.z); a0q[qi][7] = (__bf16)(kb.w * qb_.w);
            a1q[qi][0] = (__bf16)(kc.x * qc.x); a1q[qi][1] = (__bf16)(kc.y * qc.y);
            a1q[qi][2] = (__bf16)(kc.z * qc.z); a1q[qi][3] = (__bf16)(kc.w * qc.w);
            a1q[qi][4] = (__bf16)(kd.x * qd.x); a1q[qi][5] = (__bf16)(kd.y * qd.y);
            a1q[qi][6] = (__bf16)(kd.z * qd.z); a1q[qi][7] = (__bf16)(kd.w * qd.w);
        }

        float rowAcc[2][4] = {};
        const int swz = r15 & 7;

        // one 16x16 score tile at t0 (both q's); column sums via direct
        // all-lane fire-and-forget LDS atomicAdd (no shuffles in the chain)
        auto do_tile = [&](int t0, const bf16x8& b0, const bf16x8& b1) {
            #pragma unroll
            for (int qi = 0; qi < 2; ++qi) {
                const int qv = qs2[qi];
                if (t0 >= qv || s0 + 2 > qv) continue;   // wave-uniform skip
                floatx4 C = {0.f, 0.f, 0.f, 0.f};
                C = __builtin_amdgcn_mfma_f32_16x16x32_bf16(a0q[qi], b0, C, 0, 0, 0);
                C = __builtin_amdgcn_mfma_f32_16x16x32_bf16(a1q[qi], b1, C, 0, 0, 0);

                float e[4];
                if (t0 >= s0 + 16 && t0 + 16 <= qv) {    // interior: no masking
                    #pragma unroll
                    for (int i = 0; i < 4; ++i) e[i] = __expf(C[i]);
                } else {
                    const int t = t0 + r15;
                    #pragma unroll
                    for (int i = 0; i < 4; ++i) {
                        const int s = s0 + quad * 4 + i;
                        e[i] = (s < t && t < qv) ? __expf(C[i]) : 0.f;
                    }
                }
                #pragma unroll
                for (int i = 0; i < 4; ++i) rowAcc[qi][i] += e[i];
                atomicAdd(&c_lds[qi][t0 + r15], (e[0] + e[1]) + (e[2] + e[3]));
            }
        };

        for (int t0 = s0; t0 < qmax; t0 += 32) {
            const __bf16* K2rowA = &K2sh[(t0 + r15) * HH];
            const bf16x8 b0a = *(const bf16x8*)&K2rowA[((quad    ) ^ swz) << 3];
            const bf16x8 b1a = *(const bf16x8*)&K2rowA[((quad + 4) ^ swz) << 3];
            const bool two = (t0 + 16 < qmax);
            bf16x8 b0b, b1b;
            if (two) {
                const __bf16* K2rowB = &K2sh[(t0 + 16 + r15) * HH];
                b0b = *(const bf16x8*)&K2rowB[((quad    ) ^ swz) << 3];
                b1b = *(const bf16x8*)&K2rowB[((quad + 4) ^ swz) << 3];
            }
            do_tile(t0, b0a, b1a);
            if (two) do_tile(t0 + 16, b0b, b1b);
        }

        // row (s) sums: butterfly over the 16 column-lanes; strip-exclusive rows
        #pragma unroll
        for (int qi = 0; qi < 2; ++qi) {
            if (s0 + 2 > qs2[qi]) continue;
            #pragma unroll
            for (int i = 0; i < 4; ++i) {
                rowAcc[qi][i] += __shfl_xor(rowAcc[qi][i], 1, 64);
                rowAcc[qi][i] += __shfl_xor(rowAcc[qi][i], 2, 64);
                rowAcc[qi][i] += __shfl_xor(rowAcc[qi][i], 4, 64);
                rowAcc[qi][i] += __shfl_xor(rowAcc[qi][i], 8, 64);
            }
            if (r15 == 0) {
                #pragma unroll
                for (int i = 0; i < 4; ++i)
                    a_lds[qi][s0 + quad * 4 + i] = rowAcc[qi][i];
            }
        }
    }
    __syncthreads();

    // ---- Z per q (q<2 presets sum to exactly 1.0 -> invZ = 1) ---------------
    #pragma unroll
    for (int qi = 0; qi < 2; ++qi) {
        float v = a_lds[qi][tid];
        #pragma unroll
        for (int off = 32; off >= 1; off >>= 1) v += __shfl_xor(v, off, 64);
        if (lane == 0) red[qi][wid] = v;
    }
    __syncthreads();
    float invZ[2];
    #pragma unroll
    for (int qi = 0; qi < 2; ++qi)
        invZ[qi] = 1.0f / (red[qi][0] + red[qi][1] + red[qi][2] + red[qi][3]);

    // ---- z = (sum_s a_s VA[s] + sum_t c_t VB[t]) * invZ + b_V12 --------------
    {
        const int h = lane;
        const int gg = wid;                 // s-range [gg*64, gg*64+64)
        const __bf16* VAp = VAbf + ((n << 8) + (gg << 6)) * HH + h;
        const __bf16* VBp = VBbf + ((n << 8) + (gg << 6)) * HH + h;
        float acc[2] = {0.f, 0.f};
        for (int i = 0; i < 64; ++i) {
            const float va = (float)VAp[i * HH];
            const float vb = (float)VBp[i * HH];
            const int si = (gg << 6) + i;
            #pragma unroll
            for (int qi = 0; qi < 2; ++qi)
                acc[qi] = fmaf(a_lds[qi][si], va,
                          fmaf(c_lds[qi][si], vb, acc[qi]));
        }
        #pragma unroll
        for (int qi = 0; qi < 2; ++qi) zred[qi][gg][h] = acc[qi];
    }
    __syncthreads();
    if (tid < 128) {    // final z rows into qsh (reused; q-row reads are done)
        const int qi = tid >> 6;
        const int h = tid & 63;
        qsh[qi][h] = (zred[qi][0][h] + zred[qi][1][h] +
                      zred[qi][2][h] + zred[qi][3][h]) * invZ[qi]
                   + bV12[n * HH + h];
    }
    __syncthreads();

    // ---- fused epilogue GEMM: out[q,:] += z[q, n-slice] . WO[n*64:, :] -------
    // wave w serves d-stripe [w*128, w*128+128) for BOTH q's (WO read amortized)
    {
        const int d0 = (wid << 7) + lane * 2;
        const float* WOp = WO + (n * HH) * DD;
        float2 acc0 = {0.f, 0.f}, acc1 = {0.f, 0.f};
        for (int h = 0; h < HH; ++h) {
            const float2 w = *(const float2*)(WOp + h * DD + d0);
            const float z0 = qsh[0][h];            // LDS broadcast
            const float z1 = qsh[1][h];
            acc0.x = fmaf(z0, w.x, acc0.x); acc0.y = fmaf(z0, w.y, acc0.y);
            acc1.x = fmaf(z1, w.x, acc1.x); acc1.y = fmaf(z1, w.y, acc1.y);
        }
        float* op0 = outp + qs2[0] * DD + d0;
        float* op1 = outp + qs2[1] * DD + d0;
        atomicAdd(op0,     acc0.x);
        atomicAdd(op0 + 1, acc0.y);
        atomicAdd(op1,     acc1.x);
        atomicAdd(op1 + 1, acc1.y);
    }
}

// ---------------------------------------------------------------------------
extern "C" void kernel_launch(void* const* d_in, const int* in_sizes, int n_in,
                              void* d_out, int out_size, void* d_ws, size_t ws_size,
                              hipStream_t stream)
{
    const float* x    = (const float*)d_in[0];
    const float* WK1  = (const float*)d_in[1];
    const float* WK2  = (const float*)d_in[2];
    const float* WQ   = (const float*)d_in[3];
    const float* WV12 = (const float*)d_in[4];
    const float* WO   = (const float*)d_in[5];
    const float* bK1  = (const float*)d_in[6];
    const float* bK2  = (const float*)d_in[7];
    const float* bQ   = (const float*)d_in[8];
    const float* bV12 = (const float*)d_in[9];
    const float* bO   = (const float*)d_in[10];
    float* out = (float*)d_out;

    float* ws  = (float*)d_ws;
    const int T = NN * SS * HH;  // 131072 elements per projected tensor
    float*  K1b  = ws + 0 * T;
    float*  Qb   = ws + 1 * T;
    __bf16* b16  = (__bf16*)(ws + 2 * T);
    __bf16* K2bf = b16 + 0 * T;   // pre-swizzled
    __bf16* VAbf = b16 + 1 * T;
    __bf16* VBbf = b16 + 2 * T;

    proj_kernel<<<384, 256, 0, stream>>>(x, WK1, WK2, WQ, WV12,
                                         bK1, bK2, bQ, bO,
                                         K1b, Qb, K2bf, VAbf, VBbf, out);
    attn_kernel<<<1024, 256, 0, stream>>>(K1b, K2bf, Qb, VAbf, VBbf, bV12,
                                          WO, out);
}

// Round 8
// 118.738 us; speedup vs baseline: 1.1744x; 1.1744x over previous
//
#include <hip/hip_runtime.h>

// Problem constants (B=1)
#define SS 256
#define DD 512
#define NN 8
#define HH 64

typedef __bf16 bf16x8 __attribute__((ext_vector_type(8)));
typedef __bf16 bf16x4 __attribute__((ext_vector_type(4)));
typedef float  floatx4 __attribute__((ext_vector_type(4)));

// ---------------------------------------------------------------------------
// Kernel A: projections via MFMA 16x16x32 bf16.
//   m=0: K1 = x@W_K1 + b_K1      -> f32 [n][256][64]
//   m=1: K2 = x@W_K2 + b_K2      -> bf16, xor-swizzled 16B chunks (attn LDS
//                                   layout: elem (p,h) at chunk (h>>3)^(p&7))
//   m=2: Qs = (x@W_Q + b_Q)/64   -> f32
//   m=3: VA = x@W_V12[:, :D]     -> bf16 plain [n][256][64]
//   m=4: VB = x@W_V12[:, D:]     -> bf16 plain
//   m=5: out[q,:] = b_O          (bias init for attn's atomic accumulation;
//                                 stream order guarantees visibility)
// grid = 6*64 = 384 blocks, 256 threads.
// ---------------------------------------------------------------------------
__global__ __launch_bounds__(256) void proj_kernel(
    const float* __restrict__ x,
    const float* __restrict__ WK1, const float* __restrict__ WK2,
    const float* __restrict__ WQ,  const float* __restrict__ WV12,
    const float* __restrict__ bK1, const float* __restrict__ bK2,
    const float* __restrict__ bQ,  const float* __restrict__ bO,
    float* __restrict__ K1b, float* __restrict__ Qb,
    __bf16* __restrict__ K2bf, __bf16* __restrict__ VAbf,
    __bf16* __restrict__ VBbf, float* __restrict__ outp)
{
    const int blk = blockIdx.x;
    const int m  = blk >> 6;        // which matrix (0..5)
    const int tid  = threadIdx.x;

    __shared__ __bf16 xsh[32 * DD];   // 32 KB, xor-swizzled 16B chunks

    if (m == 5) {                     // bias init of out (whole block branches)
        const int idx = blk & 63;
        const int q = idx * 4 + (tid >> 6);
        const int d = (tid & 63) * 8;
        const float4 b0 = *(const float4*)(bO + d);
        const float4 b1 = *(const float4*)(bO + d + 4);
        *(float4*)(outp + q * DD + d)     = b0;
        *(float4*)(outp + q * DD + d + 4) = b1;
        return;
    }

    const int pt = blk & 7;         // 8 p-tiles of 32 rows
    const int n  = (blk >> 3) & 7;  // head
    const int lane = tid & 63;
    const int wid  = tid >> 6;
    const int r15  = lane & 15;     // MFMA M/N index
    const int quad = lane >> 4;     // MFMA k-group / row-group
    const int p0 = pt * 32;

    const float* W;
    if (m == 0)      W = WK1  + n * DD * HH;
    else if (m == 1) W = WK2  + n * DD * HH;
    else if (m == 2) W = WQ   + n * DD * HH;
    else if (m == 3) W = WV12 + n * 2 * DD * HH;
    else             W = WV12 + n * 2 * DD * HH + DD * HH;

    // ---- stage x rows p0..p0+31 (f32 -> bf16, swizzled) ----------------------
    for (int it = 0; it < 8; ++it) {
        const int idx = tid + it * 256;   // chunk id 0..2047 (32 rows x 64)
        const int row = idx >> 6;
        const int c8  = idx & 63;
        const float4 xa = *(const float4*)(x + (p0 + row) * DD + c8 * 8);
        const float4 xb = *(const float4*)(x + (p0 + row) * DD + c8 * 8 + 4);
        bf16x8 v;
        v[0]=(__bf16)xa.x; v[1]=(__bf16)xa.y; v[2]=(__bf16)xa.z; v[3]=(__bf16)xa.w;
        v[4]=(__bf16)xb.x; v[5]=(__bf16)xb.y; v[6]=(__bf16)xb.z; v[7]=(__bf16)xb.w;
        *(bf16x8*)&xsh[row * DD + ((c8 ^ (row & 7)) << 3)] = v;
    }
    __syncthreads();

    // ---- MFMA: wave w -> h-tile w, both p-sub-tiles; K = 512 -----------------
    const int h0 = wid << 4;
    const int swz = r15 & 7;          // row swizzle key
    floatx4 C0 = {0.f,0.f,0.f,0.f}, C1 = {0.f,0.f,0.f,0.f};
    for (int kk = 0; kk < 16; ++kk) {
        const int c8 = (kk << 2) + quad;                 // 16B chunk of k-range
        const bf16x8 A0 = *(const bf16x8*)&xsh[ r15       * DD + ((c8 ^ swz) << 3)];
        const bf16x8 A1 = *(const bf16x8*)&xsh[(16 + r15) * DD + ((c8 ^ swz) << 3)];
        const float* Wp = W + (kk * 32 + quad * 8) * HH + h0 + r15;
        bf16x8 Bv;
        #pragma unroll
        for (int j = 0; j < 8; ++j) Bv[j] = (__bf16)Wp[j * HH];
        C0 = __builtin_amdgcn_mfma_f32_16x16x32_bf16(A0, Bv, C0, 0, 0, 0);
        C1 = __builtin_amdgcn_mfma_f32_16x16x32_bf16(A1, Bv, C1, 0, 0, 0);
    }

    // ---- epilogue: bias, scale, store (C: col=r15 -> h, row=quad*4+i -> p) ---
    float bv = 0.f;
    if (m == 0)      bv = bK1[n * HH + h0 + r15];
    else if (m == 1) bv = bK2[n * HH + h0 + r15];
    else if (m == 2) bv = bQ[n * HH + h0 + r15];

    if (m == 1) {
        const int h = h0 + r15;
        const int c8 = h >> 3;
        #pragma unroll
        for (int i = 0; i < 4; ++i) {
            int p = p0 + quad * 4 + i;
            K2bf[(n * SS + p) * HH + ((c8 ^ (p & 7)) << 3) + (h & 7)] =
                (__bf16)(C0[i] + bv);
            p += 16;
            K2bf[(n * SS + p) * HH + ((c8 ^ (p & 7)) << 3) + (h & 7)] =
                (__bf16)(C1[i] + bv);
        }
    } else if (m >= 3) {
        __bf16* outb = (m == 3) ? VAbf : VBbf;
        #pragma unroll
        for (int i = 0; i < 4; ++i) {
            const int p = p0 + quad * 4 + i;
            outb[(n * SS + p) * HH + h0 + r15]      = (__bf16)C0[i];
            outb[(n * SS + p + 16) * HH + h0 + r15] = (__bf16)C1[i];
        }
    } else {
        float* outb = (m == 0) ? K1b : Qb;
        const float scale = (m == 2) ? (1.0f / 64.0f) : 1.0f;  // fold 1/H into Q
        #pragma unroll
        for (int i = 0; i < 4; ++i) {
            const int p = p0 + quad * 4 + i;
            outb[(n * SS + p) * HH + h0 + r15]      = (C0[i] + bv) * scale;
            outb[(n * SS + p + 16) * HH + h0 + r15] = (C1[i] + bv) * scale;
        }
    }
}

// ---------------------------------------------------------------------------
// Kernel B: block = (n, q-pair {g, 255-g}), 1024 blocks = 4 blocks/CU.
// R8 change (post R7 post-mortem): column sums accumulate in statically-
// indexed REGISTERS colAcc[qi][tau] over 4-tile chunks; the shuffle+atomic
// reduction is batched once per chunk, so the per-tile critical path is
// pure ds_read -> MFMA -> exp -> VALU adds (no DS round-trips).  R6's
// in-loop shuffles and R7's colliding in-loop LDS atomics are both gone.
// Masked entries are exactly 0 in the reference (exp underflow) so excluding
// them is exact; q<2 rows fully masked -> preset uniform 1/256.
// z[q,n,:] = (sum_s a_s VA[s] + sum_t c_t VB[t]) * invZ + b_V12, then the
// block's out-contribution z . WO[n*64:(n+1)*64, :] is atomicAdd-ed into out
// (bias pre-written by proj; stream order + device-scope atomics = safe).
// ---------------------------------------------------------------------------
__global__ __launch_bounds__(256, 4) void attn_kernel(
    const float* __restrict__ K1b, const __bf16* __restrict__ K2bf,
    const float* __restrict__ Qb,  const __bf16* __restrict__ VAbf,
    const __bf16* __restrict__ VBbf, const float* __restrict__ bV12,
    const float* __restrict__ WO, float* __restrict__ outp)
{
    const int n = blockIdx.x & 7;            // %8: same head -> same XCD L2
    const int g = (int)(blockIdx.x >> 3);    // 0..127
    int qs2[2];
    qs2[0] = g; qs2[1] = 255 - g;
    const int qmax = qs2[1];                 // >= 128 always

    const int tid  = threadIdx.x;
    const int lane = tid & 63;
    const int wid  = tid >> 6;
    const int r15  = lane & 15;   // MFMA free-dim (t) index
    const int quad = lane >> 4;   // MFMA k-group / s-row group

    __shared__ __bf16 K2sh[SS * HH];   // 32 KB, already swizzled by proj
    __shared__ float qsh[2][HH];       // q rows; later reused for final z rows
    __shared__ float a_lds[2][SS];
    __shared__ float c_lds[2][SS];
    __shared__ float zred[2][4][HH];
    __shared__ float red[2][4];

    // ---- stage K2 (plain bf16 copy) + the 2 q rows ---------------------------
    {
        const __bf16* src = K2bf + (n << 8) * HH;
        for (int it = 0; it < 8; ++it) {
            const int idx = tid + it * 256;  // 2048 16B chunks
            *(bf16x8*)&K2sh[idx * 8] = *(const bf16x8*)&src[idx * 8];
        }
        if (tid < 32) {
            const int qi = tid >> 4, c = tid & 15;
            const float4 qv = *(const float4*)(Qb + ((n << 8) + qs2[qi]) * HH + c * 4);
            *(float4*)&qsh[qi][c * 4] = qv;
        }
        #pragma unroll
        for (int qi = 0; qi < 2; ++qi) {
            const float init = (qs2[qi] < 2) ? (1.0f / SS) : 0.f;
            a_lds[qi][tid] = init;
            c_lds[qi][tid] = init;
        }
    }
    __syncthreads();

    // ---- score strips (rolled loop: body is large after chunk unroll) --------
    for (int j = 0; j < 4; ++j) {
        int strip;
        if (j == 0) strip = wid;
        else if (j == 1) strip = 7 - wid;
        else if (j == 2) strip = 8 + wid;
        else strip = 15 - wid;
        const int s0 = strip << 4;
        if (s0 + 2 > qmax) continue;

        // k1 fragment rows (shared across the 2 q's)
        const float* k1p = K1b + ((n << 8) + s0 + r15) * HH;
        const float4 ka = *(const float4*)(k1p + quad * 8);
        const float4 kb = *(const float4*)(k1p + quad * 8 + 4);
        const float4 kc = *(const float4*)(k1p + 32 + quad * 8);
        const float4 kd = *(const float4*)(k1p + 32 + quad * 8 + 4);

        bf16x8 a0q[2], a1q[2];
        #pragma unroll
        for (int qi = 0; qi < 2; ++qi) {
            const float4 qa = *(const float4*)&qsh[qi][quad * 8];
            const float4 qb_ = *(const float4*)&qsh[qi][quad * 8 + 4];
            const float4 qc = *(const float4*)&qsh[qi][32 + quad * 8];
            const float4 qd = *(const float4*)&qsh[qi][32 + quad * 8 + 4];
            a0q[qi][0] = (__bf16)(ka.x * qa.x); a0q[qi][1] = (__bf16)(ka.y * qa.y);
            a0q[qi][2] = (__bf16)(ka.z * qa.z); a0q[qi][3] = (__bf16)(ka.w * qa.w);
            a0q[qi][4] = (__bf16)(kb.x * qb_.x); a0q[qi][5] = (__bf16)(kb.y * qb_.y);
            a0q[qi][6] = (__bf16)(kb.z * qb_.z); a0q[qi][7] = (__bf16)(kb.w * qb_.w);
            a1q[qi][0] = (__bf16)(kc.x * qc.x); a1q[qi][1] = (__bf16)(kc.y * qc.y);
            a1q[qi][2] = (__bf16)(kc.z * qc.z); a1q[qi][3] = (__bf16)(kc.w * qc.w);
            a1q[qi][4] = (__bf16)(kd.x * qd.x); a1q[qi][5] = (__bf16)(kd.y * qd.y);
            a1q[qi][6] = (__bf16)(kd.z * qd.z); a1q[qi][7] = (__bf16)(kd.w * qd.w);
        }

        float rowAcc[2][4] = {};
        const int swz = r15 & 7;

        // 4-tile chunks; colAcc in registers (static indices), flushed per chunk
        for (int tb = s0; tb < qmax; tb += 64) {
            float colAcc[2][4] = {};
            #pragma unroll
            for (int tau = 0; tau < 4; ++tau) {
                const int t0 = tb + (tau << 4);
                if (t0 >= qmax) continue;               // wave-uniform
                const __bf16* K2row = &K2sh[(t0 + r15) * HH];
                const bf16x8 b0 = *(const bf16x8*)&K2row[((quad    ) ^ swz) << 3];
                const bf16x8 b1 = *(const bf16x8*)&K2row[((quad + 4) ^ swz) << 3];
                #pragma unroll
                for (int qi = 0; qi < 2; ++qi) {
                    const int qv = qs2[qi];
                    if (t0 >= qv || s0 + 2 > qv) continue;   // wave-uniform skip
                    floatx4 C = {0.f, 0.f, 0.f, 0.f};
                    C = __builtin_amdgcn_mfma_f32_16x16x32_bf16(a0q[qi], b0, C, 0, 0, 0);
                    C = __builtin_amdgcn_mfma_f32_16x16x32_bf16(a1q[qi], b1, C, 0, 0, 0);

                    float e[4];
                    if (t0 >= s0 + 16 && t0 + 16 <= qv) {    // interior
                        #pragma unroll
                        for (int i = 0; i < 4; ++i) e[i] = __expf(C[i]);
                    } else {
                        const int t = t0 + r15;
                        #pragma unroll
                        for (int i = 0; i < 4; ++i) {
                            const int s = s0 + quad * 4 + i;
                            e[i] = (s < t && t < qv) ? __expf(C[i]) : 0.f;
                        }
                    }
                    #pragma unroll
                    for (int i = 0; i < 4; ++i) rowAcc[qi][i] += e[i];
                    colAcc[qi][tau] += (e[0] + e[1]) + (e[2] + e[3]);
                }
            }
            // flush chunk: batched shuffles + conflict-free 16-lane atomics
            #pragma unroll
            for (int tau = 0; tau < 4; ++tau) {
                const int t0 = tb + (tau << 4);
                #pragma unroll
                for (int qi = 0; qi < 2; ++qi) {
                    if (t0 < qs2[qi] && s0 + 2 <= qs2[qi]) {
                        float cs = colAcc[qi][tau];
                        cs += __shfl_xor(cs, 16, 64);
                        cs += __shfl_xor(cs, 32, 64);
                        if (lane < 16) atomicAdd(&c_lds[qi][t0 + r15], cs);
                    }
                }
            }
        }

        // row (s) sums: butterfly over the 16 column-lanes; strip-exclusive rows
        #pragma unroll
        for (int qi = 0; qi < 2; ++qi) {
            if (s0 + 2 > qs2[qi]) continue;
            #pragma unroll
            for (int i = 0; i < 4; ++i) {
                rowAcc[qi][i] += __shfl_xor(rowAcc[qi][i], 1, 64);
                rowAcc[qi][i] += __shfl_xor(rowAcc[qi][i], 2, 64);
                rowAcc[qi][i] += __shfl_xor(rowAcc[qi][i], 4, 64);
                rowAcc[qi][i] += __shfl_xor(rowAcc[qi][i], 8, 64);
            }
            if (r15 == 0) {
                #pragma unroll
                for (int i = 0; i < 4; ++i)
                    a_lds[qi][s0 + quad * 4 + i] = rowAcc[qi][i];
            }
        }
    }
    __syncthreads();

    // ---- Z per q (q<2 presets sum to exactly 1.0 -> invZ = 1) ---------------
    #pragma unroll
    for (int qi = 0; qi < 2; ++qi) {
        float v = a_lds[qi][tid];
        #pragma unroll
        for (int off = 32; off >= 1; off >>= 1) v += __shfl_xor(v, off, 64);
        if (lane == 0) red[qi][wid] = v;
    }
    __syncthreads();
    float invZ[2];
    #pragma unroll
    for (int qi = 0; qi < 2; ++qi)
        invZ[qi] = 1.0f / (red[qi][0] + red[qi][1] + red[qi][2] + red[qi][3]);

    // ---- z = (sum_s a_s VA[s] + sum_t c_t VB[t]) * invZ + b_V12 --------------
    {
        const int h = lane;
        const int gg = wid;                 // s-range [gg*64, gg*64+64)
        const __bf16* VAp = VAbf + ((n << 8) + (gg << 6)) * HH + h;
        const __bf16* VBp = VBbf + ((n << 8) + (gg << 6)) * HH + h;
        float acc[2] = {0.f, 0.f};
        for (int i = 0; i < 64; ++i) {
            const float va = (float)VAp[i * HH];
            const float vb = (float)VBp[i * HH];
            const int si = (gg << 6) + i;
            #pragma unroll
            for (int qi = 0; qi < 2; ++qi)
                acc[qi] = fmaf(a_lds[qi][si], va,
                          fmaf(c_lds[qi][si], vb, acc[qi]));
        }
        #pragma unroll
        for (int qi = 0; qi < 2; ++qi) zred[qi][gg][h] = acc[qi];
    }
    __syncthreads();
    if (tid < 128) {    // final z rows into qsh (reused; q-row reads are done)
        const int qi = tid >> 6;
        const int h = tid & 63;
        qsh[qi][h] = (zred[qi][0][h] + zred[qi][1][h] +
                      zred[qi][2][h] + zred[qi][3][h]) * invZ[qi]
                   + bV12[n * HH + h];
    }
    __syncthreads();

    // ---- fused epilogue GEMM: out[q,:] += z[q, n-slice] . WO[n*64:, :] -------
    // wave w serves d-stripe [w*128, w*128+128) for BOTH q's (WO read amortized)
    {
        const int d0 = (wid << 7) + lane * 2;
        const float* WOp = WO + (n * HH) * DD;
        float2 acc0 = {0.f, 0.f}, acc1 = {0.f, 0.f};
        for (int h = 0; h < HH; ++h) {
            const float2 w = *(const float2*)(WOp + h * DD + d0);
            const float z0 = qsh[0][h];            // LDS broadcast
            const float z1 = qsh[1][h];
            acc0.x = fmaf(z0, w.x, acc0.x); acc0.y = fmaf(z0, w.y, acc0.y);
            acc1.x = fmaf(z1, w.x, acc1.x); acc1.y = fmaf(z1, w.y, acc1.y);
        }
        float* op0 = outp + qs2[0] * DD + d0;
        float* op1 = outp + qs2[1] * DD + d0;
        atomicAdd(op0,     acc0.x);
        atomicAdd(op0 + 1, acc0.y);
        atomicAdd(op1,     acc1.x);
        atomicAdd(op1 + 1, acc1.y);
    }
}

// ---------------------------------------------------------------------------
extern "C" void kernel_launch(void* const* d_in, const int* in_sizes, int n_in,
                              void* d_out, int out_size, void* d_ws, size_t ws_size,
                              hipStream_t stream)
{
    const float* x    = (const float*)d_in[0];
    const float* WK1  = (const float*)d_in[1];
    const float* WK2  = (const float*)d_in[2];
    const float* WQ   = (const float*)d_in[3];
    const float* WV12 = (const float*)d_in[4];
    const float* WO   = (const float*)d_in[5];
    const float* bK1  = (const float*)d_in[6];
    const float* bK2  = (const float*)d_in[7];
    const float* bQ   = (const float*)d_in[8];
    const float* bV12 = (const float*)d_in[9];
    const float* bO   = (const float*)d_in[10];
    float* out = (float*)d_out;

    float* ws  = (float*)d_ws;
    const int T = NN * SS * HH;  // 131072 elements per projected tensor
    float*  K1b  = ws + 0 * T;
    float*  Qb   = ws + 1 * T;
    __bf16* b16  = (__bf16*)(ws + 2 * T);
    __bf16* K2bf = b16 + 0 * T;   // pre-swizzled
    __bf16* VAbf = b16 + 1 * T;
    __bf16* VBbf = b16 + 2 * T;

    proj_kernel<<<384, 256, 0, stream>>>(x, WK1, WK2, WQ, WV12,
                                         bK1, bK2, bQ, bO,
                                         K1b, Qb, K2bf, VAbf, VBbf, out);
    attn_kernel<<<1024, 256, 0, stream>>>(K1b, K2bf, Qb, VAbf, VBbf, bV12,
                                          WO, out);
}